// Round 2
// baseline (114.484 us; speedup 1.0000x reference)
//
#include <hip/hip_runtime.h>

// AdaCoF sampler: out[b,c,h,w] = sum_k weights[b,k,h,w] * bilinear(image[b,c], y+dy, x+dx)
// B=4, C=3, H=W=256, K2=49.
// Memory-bound in principle (154 MB offsets+weights stream), but R1 counters
// showed latency-bound (13.5% HBM, VALUBusy 15%, VGPR 28 => no unroll).
// R2: batch loads in groups of 7 k's for MLP; nontemporal streaming loads.

#define BB 4
#define CC 3
#define HH 256
#define WW 256
#define K2 49
#define HWSZ (HH * WW)
#define UNROLL 7

// Interleave image (b,c,h,w) -> (b,h,w,4) float4 (c in .x/.y/.z, .w pad)
__global__ void __launch_bounds__(256)
adacof_transpose(const float* __restrict__ img, float4* __restrict__ ws) {
    int tid = blockIdx.x * blockDim.x + threadIdx.x;  // b*HW + hw
    int b = tid >> 16;
    int hw = tid & (HWSZ - 1);
    const float* base = img + (size_t)b * (CC * HWSZ) + hw;
    float4 v;
    v.x = base[0];
    v.y = base[HWSZ];
    v.z = base[2 * HWSZ];
    v.w = 0.0f;
    ws[tid] = v;
}

__global__ void __launch_bounds__(256)
adacof_main(const float4* __restrict__ img4,
            const float* __restrict__ offsets,
            const float* __restrict__ weights,
            float* __restrict__ out) {
    int tid = blockIdx.x * blockDim.x + threadIdx.x;
    int b = tid >> 16;
    int hw = tid & (HWSZ - 1);
    int y = hw >> 8;
    int x = hw & (WW - 1);

    const float* offB = offsets + (size_t)b * (2 * K2 * HWSZ) + hw;
    const float* wgtB = weights + (size_t)b * (K2 * HWSZ) + hw;
    const float4* imgB = img4 + (size_t)b * HWSZ;

    const float scale = 256.0f / 255.0f;
    float fx = (float)x;
    float fy = (float)y;

    float acc0 = 0.0f, acc1 = 0.0f, acc2 = 0.0f;

    for (int kb = 0; kb < K2; kb += UNROLL) {
        // Phase 1: batch all streaming loads for this group -> 21 loads in flight.
        float dxv[UNROLL], dyv[UNROLL], wgv[UNROLL];
        #pragma unroll
        for (int u = 0; u < UNROLL; ++u) {
            int k = kb + u;
            dxv[u] = __builtin_nontemporal_load(&offB[(size_t)(2 * k) * HWSZ]);
            dyv[u] = __builtin_nontemporal_load(&offB[(size_t)(2 * k + 1) * HWSZ]);
            wgv[u] = __builtin_nontemporal_load(&wgtB[(size_t)k * HWSZ]);
        }
        // Phase 2: addresses + gathers + FMA (7 independent bodies, compiler
        // software-pipelines the 28 gathers).
        #pragma unroll
        for (int u = 0; u < UNROLL; ++u) {
            float px = (fx + dxv[u]) * scale - 0.5f;
            float py = (fy + dyv[u]) * scale - 0.5f;
            px = fminf(fmaxf(px, 0.0f), 255.0f);
            py = fminf(fmaxf(py, 0.0f), 255.0f);

            float x0f = floorf(px);
            float y0f = floorf(py);
            float wx = px - x0f;
            float wy = py - y0f;
            int x0 = (int)x0f;
            int y0 = (int)y0f;
            int x1 = min(x0 + 1, WW - 1);
            int y1 = min(y0 + 1, HH - 1);

            float4 v00 = imgB[y0 * WW + x0];
            float4 v01 = imgB[y0 * WW + x1];
            float4 v10 = imgB[y1 * WW + x0];
            float4 v11 = imgB[y1 * WW + x1];

            float w00 = (1.0f - wx) * (1.0f - wy);
            float w01 = wx * (1.0f - wy);
            float w10 = (1.0f - wx) * wy;
            float w11 = wx * wy;

            float wgt = wgv[u];
            float b0 = v00.x * w00 + v01.x * w01 + v10.x * w10 + v11.x * w11;
            float b1 = v00.y * w00 + v01.y * w01 + v10.y * w10 + v11.y * w11;
            float b2 = v00.z * w00 + v01.z * w01 + v10.z * w10 + v11.z * w11;

            acc0 = fmaf(wgt, b0, acc0);
            acc1 = fmaf(wgt, b1, acc1);
            acc2 = fmaf(wgt, b2, acc2);
        }
    }

    float* outB = out + (size_t)b * (CC * HWSZ) + hw;
    outB[0] = acc0;
    outB[HWSZ] = acc1;
    outB[2 * HWSZ] = acc2;
}

// Fallback if d_ws is too small: gather 3 planes directly.
__global__ void __launch_bounds__(256)
adacof_direct(const float* __restrict__ img,
              const float* __restrict__ offsets,
              const float* __restrict__ weights,
              float* __restrict__ out) {
    int tid = blockIdx.x * blockDim.x + threadIdx.x;
    int b = tid >> 16;
    int hw = tid & (HWSZ - 1);
    int y = hw >> 8;
    int x = hw & (WW - 1);

    const float* offB = offsets + (size_t)b * (2 * K2 * HWSZ) + hw;
    const float* wgtB = weights + (size_t)b * (K2 * HWSZ) + hw;
    const float* imgB = img + (size_t)b * (CC * HWSZ);

    const float scale = 256.0f / 255.0f;
    float fx = (float)x;
    float fy = (float)y;

    float acc0 = 0.0f, acc1 = 0.0f, acc2 = 0.0f;

    for (int k = 0; k < K2; ++k) {
        float dx = offB[(size_t)(2 * k) * HWSZ];
        float dy = offB[(size_t)(2 * k + 1) * HWSZ];
        float wgt = wgtB[(size_t)k * HWSZ];

        float px = (fx + dx) * scale - 0.5f;
        float py = (fy + dy) * scale - 0.5f;
        px = fminf(fmaxf(px, 0.0f), 255.0f);
        py = fminf(fmaxf(py, 0.0f), 255.0f);

        float x0f = floorf(px);
        float y0f = floorf(py);
        float wx = px - x0f;
        float wy = py - y0f;
        int x0 = (int)x0f;
        int y0 = (int)y0f;
        int x1 = min(x0 + 1, WW - 1);
        int y1 = min(y0 + 1, HH - 1);

        int i00 = y0 * WW + x0;
        int i01 = y0 * WW + x1;
        int i10 = y1 * WW + x0;
        int i11 = y1 * WW + x1;

        float w00 = (1.0f - wx) * (1.0f - wy);
        float w01 = wx * (1.0f - wy);
        float w10 = (1.0f - wx) * wy;
        float w11 = wx * wy;

        #pragma unroll
        for (int c = 0; c < CC; ++c) {
            const float* p = imgB + (size_t)c * HWSZ;
            float bil = p[i00] * w00 + p[i01] * w01 + p[i10] * w10 + p[i11] * w11;
            if (c == 0) acc0 = fmaf(wgt, bil, acc0);
            else if (c == 1) acc1 = fmaf(wgt, bil, acc1);
            else acc2 = fmaf(wgt, bil, acc2);
        }
    }

    float* outB = out + (size_t)b * (CC * HWSZ) + hw;
    outB[0] = acc0;
    outB[HWSZ] = acc1;
    outB[2 * HWSZ] = acc2;
}

extern "C" void kernel_launch(void* const* d_in, const int* in_sizes, int n_in,
                              void* d_out, int out_size, void* d_ws, size_t ws_size,
                              hipStream_t stream) {
    const float* image = (const float*)d_in[0];
    const float* offsets = (const float*)d_in[1];
    const float* weights = (const float*)d_in[2];
    float* out = (float*)d_out;

    const int total = BB * HWSZ;          // 262144 threads, one per (b,h,w)
    const int block = 256;
    const int grid = total / block;       // 1024 blocks

    const size_t ws_needed = (size_t)BB * HWSZ * 4 * sizeof(float);  // 4 MB

    if (ws_size >= ws_needed) {
        adacof_transpose<<<grid, block, 0, stream>>>(image, (float4*)d_ws);
        adacof_main<<<grid, block, 0, stream>>>((const float4*)d_ws, offsets, weights, out);
    } else {
        adacof_direct<<<grid, block, 0, stream>>>(image, offsets, weights, out);
    }
}

// Round 3
// 68.401 us; speedup vs baseline: 1.6737x; 1.6737x over previous
//
#include <hip/hip_runtime.h>

// AdaCoF sampler: out[b,c,h,w] = sum_k weights[b,k,h,w] * bilinear(image[b,c], y+dy, x+dx)
// B=4, C=3, H=W=256, K2=49.
// R1/R2 post-mortem: latency-bound (HBM 11-13%, VALUBusy 16%, occupancy 40%
// -- grid supplies only 4096 waves / 8192 slots and each wave serializes on
// per-tap load latency; compiler sank "batched" loads back to uses).
// R3: split k 7-ways across threads (B*7*HW threads = 28672 waves, ~100%
// occupancy), batch the 21 streaming loads behind sched_barrier(0), write
// partials to ws, reduce in a second pass. No nontemporal (hurt in R2).

#define BB 4
#define CC 3
#define HH 256
#define WW 256
#define K2 49
#define HWSZ (HH * WW)
#define NG 7              // k-groups
#define KPG 7             // k's per group

// ---------- pass 0: interleave image (b,c,h,w) -> (b,h,w,4) float4 ----------
__global__ void __launch_bounds__(256)
adacof_transpose(const float* __restrict__ img, float4* __restrict__ img4) {
    int tid = blockIdx.x * blockDim.x + threadIdx.x;  // b*HW + hw
    int b = tid >> 16;
    int hw = tid & (HWSZ - 1);
    const float* base = img + (size_t)b * (CC * HWSZ) + hw;
    float4 v;
    v.x = base[0];
    v.y = base[HWSZ];
    v.z = base[2 * HWSZ];
    v.w = 0.0f;
    img4[tid] = v;
}

// ---------- pass 1: partial sums over 7 taps per thread ----------
// thread id = (b*NG + g)*HWSZ + hw ; handles k in [g*KPG, g*KPG+KPG)
// partial layout: [(b*NG + g)*CC + c][hw]
__global__ void __launch_bounds__(256)
adacof_partial(const float4* __restrict__ img4,
               const float* __restrict__ offsets,
               const float* __restrict__ weights,
               float* __restrict__ partial) {
    int tid = blockIdx.x * blockDim.x + threadIdx.x;
    int hw = tid & (HWSZ - 1);
    int rest = tid >> 16;          // uniform within a block
    int g = rest % NG;
    int b = rest / NG;
    int y = hw >> 8;
    int x = hw & (WW - 1);

    const float* offB = offsets + (size_t)b * (2 * K2 * HWSZ) + hw;
    const float* wgtB = weights + (size_t)b * (K2 * HWSZ) + hw;
    const float4* imgB = img4 + (size_t)b * HWSZ;

    const float scale = 256.0f / 255.0f;
    float fx = (float)x;
    float fy = (float)y;

    // Phase 1: all 21 streaming loads in flight.
    float dxv[KPG], dyv[KPG], wgv[KPG];
    #pragma unroll
    for (int j = 0; j < KPG; ++j) {
        int k = g * KPG + j;
        dxv[j] = offB[(size_t)(2 * k) * HWSZ];
        dyv[j] = offB[(size_t)(2 * k + 1) * HWSZ];
        wgv[j] = wgtB[(size_t)k * HWSZ];
    }
    __builtin_amdgcn_sched_barrier(0);   // don't sink the loads into the bodies

    float acc0 = 0.0f, acc1 = 0.0f, acc2 = 0.0f;
    #pragma unroll
    for (int j = 0; j < KPG; ++j) {
        float px = (fx + dxv[j]) * scale - 0.5f;
        float py = (fy + dyv[j]) * scale - 0.5f;
        px = fminf(fmaxf(px, 0.0f), 255.0f);
        py = fminf(fmaxf(py, 0.0f), 255.0f);

        float x0f = floorf(px);
        float y0f = floorf(py);
        float wx = px - x0f;
        float wy = py - y0f;
        int x0 = (int)x0f;
        int y0 = (int)y0f;
        int x1 = min(x0 + 1, WW - 1);
        int y1 = min(y0 + 1, HH - 1);

        float4 v00 = imgB[y0 * WW + x0];
        float4 v01 = imgB[y0 * WW + x1];
        float4 v10 = imgB[y1 * WW + x0];
        float4 v11 = imgB[y1 * WW + x1];

        float w00 = (1.0f - wx) * (1.0f - wy);
        float w01 = wx * (1.0f - wy);
        float w10 = (1.0f - wx) * wy;
        float w11 = wx * wy;

        float wgt = wgv[j];
        float b0 = v00.x * w00 + v01.x * w01 + v10.x * w10 + v11.x * w11;
        float b1 = v00.y * w00 + v01.y * w01 + v10.y * w10 + v11.y * w11;
        float b2 = v00.z * w00 + v01.z * w01 + v10.z * w10 + v11.z * w11;

        acc0 = fmaf(wgt, b0, acc0);
        acc1 = fmaf(wgt, b1, acc1);
        acc2 = fmaf(wgt, b2, acc2);
    }

    float* pB = partial + ((size_t)(rest) * CC) * HWSZ + hw;  // rest = b*NG+g
    pB[0] = acc0;
    pB[HWSZ] = acc1;
    pB[2 * HWSZ] = acc2;
}

// ---------- pass 2: reduce the 7 partials ----------
// thread id = (b*CC + c)*HWSZ + hw  == flat out index
__global__ void __launch_bounds__(256)
adacof_reduce(const float* __restrict__ partial, float* __restrict__ out) {
    int tid = blockIdx.x * blockDim.x + threadIdx.x;
    int hw = tid & (HWSZ - 1);
    int rest = tid >> 16;          // b*CC + c
    int c = rest % CC;
    int b = rest / CC;

    const float* pB = partial + ((size_t)(b * NG) * CC + c) * HWSZ + hw;
    float s = 0.0f;
    #pragma unroll
    for (int g = 0; g < NG; ++g)
        s += pB[(size_t)g * CC * HWSZ];
    out[tid] = s;
}

// ---------- fallback: one thread per pixel, all 49 taps ----------
__global__ void __launch_bounds__(256)
adacof_direct(const float* __restrict__ img,
              const float* __restrict__ offsets,
              const float* __restrict__ weights,
              float* __restrict__ out) {
    int tid = blockIdx.x * blockDim.x + threadIdx.x;
    int b = tid >> 16;
    int hw = tid & (HWSZ - 1);
    int y = hw >> 8;
    int x = hw & (WW - 1);

    const float* offB = offsets + (size_t)b * (2 * K2 * HWSZ) + hw;
    const float* wgtB = weights + (size_t)b * (K2 * HWSZ) + hw;
    const float* imgB = img + (size_t)b * (CC * HWSZ);

    const float scale = 256.0f / 255.0f;
    float fx = (float)x;
    float fy = (float)y;

    float acc0 = 0.0f, acc1 = 0.0f, acc2 = 0.0f;

    for (int k = 0; k < K2; ++k) {
        float dx = offB[(size_t)(2 * k) * HWSZ];
        float dy = offB[(size_t)(2 * k + 1) * HWSZ];
        float wgt = wgtB[(size_t)k * HWSZ];

        float px = (fx + dx) * scale - 0.5f;
        float py = (fy + dy) * scale - 0.5f;
        px = fminf(fmaxf(px, 0.0f), 255.0f);
        py = fminf(fmaxf(py, 0.0f), 255.0f);

        float x0f = floorf(px);
        float y0f = floorf(py);
        float wx = px - x0f;
        float wy = py - y0f;
        int x0 = (int)x0f;
        int y0 = (int)y0f;
        int x1 = min(x0 + 1, WW - 1);
        int y1 = min(y0 + 1, HH - 1);

        int i00 = y0 * WW + x0;
        int i01 = y0 * WW + x1;
        int i10 = y1 * WW + x0;
        int i11 = y1 * WW + x1;

        float w00 = (1.0f - wx) * (1.0f - wy);
        float w01 = wx * (1.0f - wy);
        float w10 = (1.0f - wx) * wy;
        float w11 = wx * wy;

        #pragma unroll
        for (int c = 0; c < CC; ++c) {
            const float* p = imgB + (size_t)c * HWSZ;
            float bil = p[i00] * w00 + p[i01] * w01 + p[i10] * w10 + p[i11] * w11;
            if (c == 0) acc0 = fmaf(wgt, bil, acc0);
            else if (c == 1) acc1 = fmaf(wgt, bil, acc1);
            else acc2 = fmaf(wgt, bil, acc2);
        }
    }

    float* outB = out + (size_t)b * (CC * HWSZ) + hw;
    outB[0] = acc0;
    outB[HWSZ] = acc1;
    outB[2 * HWSZ] = acc2;
}

extern "C" void kernel_launch(void* const* d_in, const int* in_sizes, int n_in,
                              void* d_out, int out_size, void* d_ws, size_t ws_size,
                              hipStream_t stream) {
    const float* image = (const float*)d_in[0];
    const float* offsets = (const float*)d_in[1];
    const float* weights = (const float*)d_in[2];
    float* out = (float*)d_out;

    const int block = 256;
    const size_t img4_bytes = (size_t)BB * HWSZ * 4 * sizeof(float);          // 4 MB
    const size_t partial_bytes = (size_t)BB * NG * CC * HWSZ * sizeof(float); // 22 MB

    if (ws_size >= img4_bytes + partial_bytes) {
        float4* img4 = (float4*)d_ws;
        float* partial = (float*)((char*)d_ws + img4_bytes);

        adacof_transpose<<<BB * HWSZ / block, block, 0, stream>>>(image, img4);
        adacof_partial<<<BB * NG * HWSZ / block, block, 0, stream>>>(
            img4, offsets, weights, partial);
        adacof_reduce<<<BB * CC * HWSZ / block, block, 0, stream>>>(partial, out);
    } else {
        adacof_direct<<<BB * HWSZ / block, block, 0, stream>>>(image, offsets, weights, out);
    }
}